// Round 1
// baseline (336.935 us; speedup 1.0000x reference)
//
#include <hip/hip_runtime.h>

#define Bb 2
#define Ss 2048
#define Dd 1024
#define Hh 16
#define HDd 64
#define BS (Bb * Ss)

typedef __attribute__((ext_vector_type(8))) __bf16 bf16x8;
typedef __attribute__((ext_vector_type(4))) float f32x4;

__device__ __forceinline__ unsigned short f2bf(float f) {
  union { float f; unsigned u; } v; v.f = f;
  unsigned r = v.u + 0x7fffu + ((v.u >> 16) & 1u);
  return (unsigned short)(r >> 16);
}
__device__ __forceinline__ float bf2f(unsigned short b) {
  union { unsigned u; float f; } v; v.u = ((unsigned)b) << 16;
  return v.f;
}

// async global->LDS, 16B per lane; LDS dest must be wave-uniform base + lane*16
__device__ __forceinline__ void gl_lds16(const void* g, void* l) {
  __builtin_amdgcn_global_load_lds(
      (const __attribute__((address_space(1))) void*)g,
      (__attribute__((address_space(3))) void*)l, 16, 0, 0);
}

// ---------------- cast fp32 -> bf16 (x, stacked wq|wk|wv, wo) ----------------
__global__ __launch_bounds__(256) void cast_all(
    const float* __restrict__ x, const float* __restrict__ wq,
    const float* __restrict__ wk, const float* __restrict__ wv,
    const float* __restrict__ wo, unsigned short* __restrict__ xb,
    unsigned short* __restrict__ wqkvb, unsigned short* __restrict__ wob) {
  int i = blockIdx.x * 256 + threadIdx.x;
  const int NX = BS * Dd;      // 4M
  const int NW = Dd * Dd;      // 1M
  if (i < NX) { xb[i] = f2bf(x[i]); return; }
  int j = i - NX;
  if (j < NW) { wqkvb[j] = f2bf(wq[j]); return; }
  j -= NW;
  if (j < NW) { wqkvb[NW + j] = f2bf(wk[j]); return; }
  j -= NW;
  if (j < NW) { wqkvb[2 * NW + j] = f2bf(wv[j]); return; }
  j -= NW;
  if (j < NW) { wob[j] = f2bf(wo[j]); }
}

// ---------------- m97-style bf16 GEMM: C[m][n] = sum_k A[m][k] * Bw[n][k] ----
// A: MxK row-major bf16. Bw: NxK row-major bf16 (B^T layout). 128x128 tile, BK=32.
template <int OUT_BF16>
__global__ __launch_bounds__(256) void gemm_bt(
    const unsigned short* __restrict__ A, const unsigned short* __restrict__ Bw,
    void* __restrict__ Cv, int M, int N, int K) {
  __shared__ __align__(16) unsigned short As[128 * 32];
  __shared__ __align__(16) unsigned short Bs[128 * 32];
  const int tid = threadIdx.x;
  const int lane = tid & 63;
  const int quad = lane >> 4;
  const int l16 = lane & 15;
  const int wave = tid >> 6;
  const int wm = (wave >> 1) * 64;
  const int wn = (wave & 1) * 64;
  const int tile_m = blockIdx.y * 128;
  const int tile_n = blockIdx.x * 128;

  // staging: 8KB tile = 2 rounds x 256 threads x 16B; row = 64B of 32 bf16
  const int off0 = tid * 16;
  const int off1 = 4096 + tid * 16;
  const int r0 = off0 >> 6, e0 = (off0 & 63) >> 1;
  const int r1 = off1 >> 6, e1 = (off1 & 63) >> 1;

  const unsigned short* Ag0 = A + (size_t)(tile_m + r0) * K + e0;
  const unsigned short* Ag1 = A + (size_t)(tile_m + r1) * K + e1;
  const unsigned short* Bg0 = Bw + (size_t)(tile_n + r0) * K + e0;
  const unsigned short* Bg1 = Bw + (size_t)(tile_n + r1) * K + e1;

  f32x4 zero = {0.f, 0.f, 0.f, 0.f};
  f32x4 acc[4][4];
#pragma unroll
  for (int mi = 0; mi < 4; ++mi)
#pragma unroll
    for (int ni = 0; ni < 4; ++ni) acc[mi][ni] = zero;

  for (int k0 = 0; k0 < K; k0 += 32) {
    gl_lds16(Ag0 + k0, (char*)As + off0);
    gl_lds16(Ag1 + k0, (char*)As + off1);
    gl_lds16(Bg0 + k0, (char*)Bs + off0);
    gl_lds16(Bg1 + k0, (char*)Bs + off1);
    __syncthreads();
    bf16x8 af[4], bfv[4];
#pragma unroll
    for (int mi = 0; mi < 4; ++mi)
      af[mi] = *(const bf16x8*)&As[(wm + mi * 16 + l16) * 32 + quad * 8];
#pragma unroll
    for (int ni = 0; ni < 4; ++ni)
      bfv[ni] = *(const bf16x8*)&Bs[(wn + ni * 16 + l16) * 32 + quad * 8];
#pragma unroll
    for (int mi = 0; mi < 4; ++mi)
#pragma unroll
      for (int ni = 0; ni < 4; ++ni)
        acc[mi][ni] = __builtin_amdgcn_mfma_f32_16x16x32_bf16(
            af[mi], bfv[ni], acc[mi][ni], 0, 0, 0);
    __syncthreads();
  }

  // C/D layout (m89-verified): col = lane&15, row = quad*4 + reg
#pragma unroll
  for (int mi = 0; mi < 4; ++mi) {
#pragma unroll
    for (int ni = 0; ni < 4; ++ni) {
      int col = tile_n + wn + ni * 16 + l16;
#pragma unroll
      for (int r = 0; r < 4; ++r) {
        int row = tile_m + wm + mi * 16 + quad * 4 + r;
        if (OUT_BF16)
          ((unsigned short*)Cv)[(size_t)row * N + col] = f2bf(acc[mi][ni][r]);
        else
          ((float*)Cv)[(size_t)row * N + col] = acc[mi][ni][r];
      }
    }
  }
}

// ---------------- RMSNorm(q,k) + RoPE + layout: Q,K->[B,H,S,HD], V->[B,H,HD,S]
__global__ __launch_bounds__(256) void normrope(
    const unsigned short* __restrict__ qkv, const float* __restrict__ qw,
    const float* __restrict__ kw, unsigned short* __restrict__ Qb,
    unsigned short* __restrict__ Kb, unsigned short* __restrict__ Vt) {
  int tid = threadIdx.x;
  int d = tid & 63;
  int rl = tid >> 6;                      // wave id = local row
  int row_id = blockIdx.x * 4 + rl;       // [0, BS*H)
  int m = row_id >> 4;                    // token index, H=16
  int h = row_id & 15;
  int b = m >> 11;                        // S=2048
  int s = m & 2047;

  size_t base = (size_t)m * (3 * Dd) + h * 64 + d;
  float qv = bf2f(qkv[base]);
  float kv = bf2f(qkv[base + Dd]);
  float vv = bf2f(qkv[base + 2 * Dd]);

  float qss = qv * qv, kss = kv * kv;
#pragma unroll
  for (int o = 32; o > 0; o >>= 1) {
    qss += __shfl_xor(qss, o, 64);
    kss += __shfl_xor(kss, o, 64);
  }
  float qr = rsqrtf(qss * (1.0f / 64.0f) + 1e-6f);
  float kr = rsqrtf(kss * (1.0f / 64.0f) + 1e-6f);
  float qn = qv * qr * qw[d];
  float kn = kv * kr * kw[d];

  float ang = (float)s * __powf(10000.0f, -(float)(d & 31) * (1.0f / 32.0f));
  float cs = cosf(ang), sn = sinf(ang);
  float qp = __shfl_xor(qn, 32, 64);
  float kp = __shfl_xor(kn, 32, 64);
  float sg = (d < 32) ? -1.0f : 1.0f;
  float qo = qn * cs + sg * qp * sn;
  float ko = kn * cs + sg * kp * sn;

  size_t oqk = (((size_t)(b * Hh + h)) * Ss + s) * HDd + d;
  Qb[oqk] = f2bf(qo);
  Kb[oqk] = f2bf(ko);
  size_t ov = (((size_t)(b * Hh + h)) * HDd + d) * Ss + s;
  Vt[ov] = f2bf(vv);
}

// ---------------- flash attention with sink, causal, 64-row Q tile ----------
__global__ __launch_bounds__(256) void flash(
    const unsigned short* __restrict__ Qb, const unsigned short* __restrict__ Kb,
    const unsigned short* __restrict__ Vt, const float* __restrict__ sink,
    unsigned short* __restrict__ Ob) {
  __shared__ __align__(16) unsigned short Qs[64 * 64];
  __shared__ __align__(16) unsigned short Ks[64 * 64];
  __shared__ __align__(16) unsigned short Vs[64 * 64];   // V^T tile [d][kv]
  __shared__ __align__(16) unsigned short Ps[4][16 * 64];

  int tid = threadIdx.x, lane = tid & 63, wave = tid >> 6;
  int quad = lane >> 4, l16 = lane & 15;
  int qt = (int)(gridDim.x - 1 - blockIdx.x);  // longest blocks first
  int h = blockIdx.y, b = blockIdx.z;
  int q0 = qt * 64;

  const unsigned short* Qg = Qb + ((size_t)(b * Hh + h) * Ss) * HDd;
  const unsigned short* Kg = Kb + ((size_t)(b * Hh + h) * Ss) * HDd;
  const unsigned short* Vg = Vt + ((size_t)(b * Hh + h) * HDd) * Ss;

  int off0 = tid * 16, off1 = 4096 + tid * 16;
  int qr0 = off0 >> 7, qe0 = (off0 & 127) >> 1;  // 128B rows of 64 bf16
  int qr1 = off1 >> 7, qe1 = (off1 & 127) >> 1;

  gl_lds16(Qg + (size_t)(q0 + qr0) * 64 + qe0, (char*)Qs + off0);
  gl_lds16(Qg + (size_t)(q0 + qr1) * 64 + qe1, (char*)Qs + off1);

  float sk = sink[h];
  float m_i[4], l_i[4];
  f32x4 zero = {0.f, 0.f, 0.f, 0.f};
  f32x4 Oacc[4];
#pragma unroll
  for (int r = 0; r < 4; ++r) { m_i[r] = sk; l_i[r] = 1.0f; }
#pragma unroll
  for (int ni = 0; ni < 4; ++ni) Oacc[ni] = zero;

  int row_g = q0 + wave * 16 + quad * 4;  // + r

  for (int kt = 0; kt <= qt; ++kt) {
    int kv0 = kt * 64;
    gl_lds16(Kg + (size_t)(kv0 + qr0) * 64 + qe0, (char*)Ks + off0);
    gl_lds16(Kg + (size_t)(kv0 + qr1) * 64 + qe1, (char*)Ks + off1);
    gl_lds16(Vg + (size_t)qr0 * Ss + kv0 + qe0, (char*)Vs + off0);
    gl_lds16(Vg + (size_t)qr1 * Ss + kv0 + qe1, (char*)Vs + off1);
    __syncthreads();

    // S = Q K^T : per-wave 16(q) x 64(kv)
    bf16x8 aq0 = *(const bf16x8*)&Qs[(wave * 16 + l16) * 64 + quad * 8];
    bf16x8 aq1 = *(const bf16x8*)&Qs[(wave * 16 + l16) * 64 + 32 + quad * 8];
    f32x4 sc[4];
#pragma unroll
    for (int ni = 0; ni < 4; ++ni) {
      bf16x8 bk0 = *(const bf16x8*)&Ks[(ni * 16 + l16) * 64 + quad * 8];
      bf16x8 bk1 = *(const bf16x8*)&Ks[(ni * 16 + l16) * 64 + 32 + quad * 8];
      sc[ni] = __builtin_amdgcn_mfma_f32_16x16x32_bf16(aq0, bk0, zero, 0, 0, 0);
      sc[ni] = __builtin_amdgcn_mfma_f32_16x16x32_bf16(aq1, bk1, sc[ni], 0, 0, 0);
    }

    bool diag = (kt == qt);
    float mt[4];
#pragma unroll
    for (int r = 0; r < 4; ++r) {
      float mm = -3.0e38f;
#pragma unroll
      for (int ni = 0; ni < 4; ++ni) {
        float v = sc[ni][r] * 0.125f;  // HD^-0.5
        if (diag && (kv0 + ni * 16 + l16 > row_g + r)) v = -1.0e38f;
        sc[ni][r] = v;
        mm = fmaxf(mm, v);
      }
      mt[r] = mm;
    }
#pragma unroll
    for (int o = 1; o < 16; o <<= 1)
#pragma unroll
      for (int r = 0; r < 4; ++r) mt[r] = fmaxf(mt[r], __shfl_xor(mt[r], o, 64));

    float alpha[4], rs[4];
#pragma unroll
    for (int r = 0; r < 4; ++r) {
      float mnew = fmaxf(m_i[r], mt[r]);
      alpha[r] = __expf(m_i[r] - mnew);
      m_i[r] = mnew;
      float ssum = 0.f;
#pragma unroll
      for (int ni = 0; ni < 4; ++ni) {
        float p = __expf(sc[ni][r] - mnew);
        sc[ni][r] = p;
        ssum += p;
      }
      rs[r] = ssum;
    }
#pragma unroll
    for (int o = 1; o < 16; o <<= 1)
#pragma unroll
      for (int r = 0; r < 4; ++r) rs[r] += __shfl_xor(rs[r], o, 64);
#pragma unroll
    for (int r = 0; r < 4; ++r) l_i[r] = l_i[r] * alpha[r] + rs[r];

    // P: C-layout -> LDS -> A-layout (per-wave region, no barrier needed)
#pragma unroll
    for (int ni = 0; ni < 4; ++ni)
#pragma unroll
      for (int r = 0; r < 4; ++r)
        Ps[wave][(quad * 4 + r) * 64 + ni * 16 + l16] = f2bf(sc[ni][r]);

#pragma unroll
    for (int ni = 0; ni < 4; ++ni)
#pragma unroll
      for (int r = 0; r < 4; ++r) Oacc[ni][r] *= alpha[r];

    bf16x8 ap0 = *(const bf16x8*)&Ps[wave][l16 * 64 + quad * 8];
    bf16x8 ap1 = *(const bf16x8*)&Ps[wave][l16 * 64 + 32 + quad * 8];
#pragma unroll
    for (int ni = 0; ni < 4; ++ni) {
      bf16x8 bv0 = *(const bf16x8*)&Vs[(ni * 16 + l16) * 64 + quad * 8];
      bf16x8 bv1 = *(const bf16x8*)&Vs[(ni * 16 + l16) * 64 + 32 + quad * 8];
      Oacc[ni] = __builtin_amdgcn_mfma_f32_16x16x32_bf16(ap0, bv0, Oacc[ni], 0, 0, 0);
      Oacc[ni] = __builtin_amdgcn_mfma_f32_16x16x32_bf16(ap1, bv1, Oacc[ni], 0, 0, 0);
    }
    __syncthreads();
  }

  // write attn out as [b, s, h*64+d] bf16 (A operand of final GEMM)
#pragma unroll
  for (int ni = 0; ni < 4; ++ni)
#pragma unroll
    for (int r = 0; r < 4; ++r) {
      int srow = row_g + r;
      Ob[((size_t)b * Ss + srow) * Dd + h * 64 + ni * 16 + l16] =
          f2bf(Oacc[ni][r] / l_i[r]);
    }
}

extern "C" void kernel_launch(void* const* d_in, const int* in_sizes, int n_in,
                              void* d_out, int out_size, void* d_ws, size_t ws_size,
                              hipStream_t stream) {
  const float* x  = (const float*)d_in[0];
  const float* wq = (const float*)d_in[1];
  const float* wk = (const float*)d_in[2];
  const float* wv = (const float*)d_in[3];
  const float* wo = (const float*)d_in[4];
  const float* qw = (const float*)d_in[5];
  const float* kw = (const float*)d_in[6];
  const float* sk = (const float*)d_in[7];

  char* ws = (char*)d_ws;
  const size_t MB = 1ull << 20;
  // layout (64 MB total): xb dies after GEMM1, attnb reuses its slot
  unsigned short* xb    = (unsigned short*)(ws + 0);       // 8 MB
  unsigned short* attnb = (unsigned short*)(ws + 0);       // 8 MB (after flash)
  unsigned short* wqkvb = (unsigned short*)(ws + 8 * MB);  // 6 MB
  unsigned short* wob   = (unsigned short*)(ws + 14 * MB); // 2 MB
  unsigned short* qkvb  = (unsigned short*)(ws + 16 * MB); // 24 MB
  unsigned short* Qb    = (unsigned short*)(ws + 40 * MB); // 8 MB
  unsigned short* Kb    = (unsigned short*)(ws + 48 * MB); // 8 MB
  unsigned short* Vt    = (unsigned short*)(ws + 56 * MB); // 8 MB

  cast_all<<<32768, 256, 0, stream>>>(x, wq, wk, wv, wo, xb, wqkvb, wob);
  gemm_bt<1><<<dim3(24, 32), 256, 0, stream>>>(xb, wqkvb, qkvb, BS, 3 * Dd, Dd);
  normrope<<<16384, 256, 0, stream>>>(qkvb, qw, kw, Qb, Kb, Vt);
  flash<<<dim3(32, Hh, Bb), 256, 0, stream>>>(Qb, Kb, Vt, sk, attnb);
  gemm_bt<0><<<dim3(8, 32), 256, 0, stream>>>(attnb, wob, d_out, BS, Dd, Dd);
}

// Round 2
// 294.943 us; speedup vs baseline: 1.1424x; 1.1424x over previous
//
#include <hip/hip_runtime.h>

#define Bb 2
#define Ss 2048
#define Dd 1024
#define Hh 16
#define HDd 64
#define BS (Bb * Ss)

typedef __attribute__((ext_vector_type(8))) __bf16 bf16x8;
typedef __attribute__((ext_vector_type(4))) float f32x4;

__device__ __forceinline__ unsigned short f2bf(float f) {
  union { float f; unsigned u; } v; v.f = f;
  unsigned r = v.u + 0x7fffu + ((v.u >> 16) & 1u);
  return (unsigned short)(r >> 16);
}
__device__ __forceinline__ float bf2f(unsigned short b) {
  union { unsigned u; float f; } v; v.u = ((unsigned)b) << 16;
  return v.f;
}

// async global->LDS, 16B per lane; LDS dest must be wave-uniform base + lane*16
__device__ __forceinline__ void gl_lds16(const void* g, void* l) {
  __builtin_amdgcn_global_load_lds(
      (const __attribute__((address_space(1))) void*)g,
      (__attribute__((address_space(3))) void*)l, 16, 0, 0);
}

// ---------------- cast fp32 -> bf16 (x, stacked wq|wk|wv, wo) ----------------
__global__ __launch_bounds__(256) void cast_all(
    const float* __restrict__ x, const float* __restrict__ wq,
    const float* __restrict__ wk, const float* __restrict__ wv,
    const float* __restrict__ wo, unsigned short* __restrict__ xb,
    unsigned short* __restrict__ wqkvb, unsigned short* __restrict__ wob) {
  int i = blockIdx.x * 256 + threadIdx.x;
  const int NX = BS * Dd;      // 4M
  const int NW = Dd * Dd;      // 1M
  if (i < NX) { xb[i] = f2bf(x[i]); return; }
  int j = i - NX;
  if (j < NW) { wqkvb[j] = f2bf(wq[j]); return; }
  j -= NW;
  if (j < NW) { wqkvb[NW + j] = f2bf(wk[j]); return; }
  j -= NW;
  if (j < NW) { wqkvb[2 * NW + j] = f2bf(wv[j]); return; }
  j -= NW;
  if (j < NW) { wob[j] = f2bf(wo[j]); }
}

// ---------------- m97-style bf16 GEMM: C[m][n] = sum_k A[m][k] * Bw[n][k] ----
// A: MxK row-major bf16. Bw: NxK row-major bf16 (B^T layout). 128x128 tile, BK=32.
template <int OUT_BF16>
__global__ __launch_bounds__(256) void gemm_bt(
    const unsigned short* __restrict__ A, const unsigned short* __restrict__ Bw,
    void* __restrict__ Cv, int M, int N, int K) {
  __shared__ __align__(16) unsigned short As[128 * 32];
  __shared__ __align__(16) unsigned short Bs[128 * 32];
  const int tid = threadIdx.x;
  const int lane = tid & 63;
  const int quad = lane >> 4;
  const int l16 = lane & 15;
  const int wave = tid >> 6;
  const int wm = (wave >> 1) * 64;
  const int wn = (wave & 1) * 64;
  const int tile_m = blockIdx.y * 128;
  const int tile_n = blockIdx.x * 128;

  // staging: 8KB tile = 2 rounds x 256 threads x 16B; row = 64B of 32 bf16
  const int off0 = tid * 16;
  const int off1 = 4096 + tid * 16;
  const int r0 = off0 >> 6, e0 = (off0 & 63) >> 1;
  const int r1 = off1 >> 6, e1 = (off1 & 63) >> 1;

  const unsigned short* Ag0 = A + (size_t)(tile_m + r0) * K + e0;
  const unsigned short* Ag1 = A + (size_t)(tile_m + r1) * K + e1;
  const unsigned short* Bg0 = Bw + (size_t)(tile_n + r0) * K + e0;
  const unsigned short* Bg1 = Bw + (size_t)(tile_n + r1) * K + e1;

  f32x4 zero = {0.f, 0.f, 0.f, 0.f};
  f32x4 acc[4][4];
#pragma unroll
  for (int mi = 0; mi < 4; ++mi)
#pragma unroll
    for (int ni = 0; ni < 4; ++ni) acc[mi][ni] = zero;

  for (int k0 = 0; k0 < K; k0 += 32) {
    gl_lds16(Ag0 + k0, (char*)As + off0);
    gl_lds16(Ag1 + k0, (char*)As + off1);
    gl_lds16(Bg0 + k0, (char*)Bs + off0);
    gl_lds16(Bg1 + k0, (char*)Bs + off1);
    __syncthreads();
    bf16x8 af[4], bfv[4];
#pragma unroll
    for (int mi = 0; mi < 4; ++mi)
      af[mi] = *(const bf16x8*)&As[(wm + mi * 16 + l16) * 32 + quad * 8];
#pragma unroll
    for (int ni = 0; ni < 4; ++ni)
      bfv[ni] = *(const bf16x8*)&Bs[(wn + ni * 16 + l16) * 32 + quad * 8];
#pragma unroll
    for (int mi = 0; mi < 4; ++mi)
#pragma unroll
      for (int ni = 0; ni < 4; ++ni)
        acc[mi][ni] = __builtin_amdgcn_mfma_f32_16x16x32_bf16(
            af[mi], bfv[ni], acc[mi][ni], 0, 0, 0);
    __syncthreads();
  }

  // C/D layout (m89-verified): col = lane&15, row = quad*4 + reg
#pragma unroll
  for (int mi = 0; mi < 4; ++mi) {
#pragma unroll
    for (int ni = 0; ni < 4; ++ni) {
      int col = tile_n + wn + ni * 16 + l16;
#pragma unroll
      for (int r = 0; r < 4; ++r) {
        int row = tile_m + wm + mi * 16 + quad * 4 + r;
        if (OUT_BF16)
          ((unsigned short*)Cv)[(size_t)row * N + col] = f2bf(acc[mi][ni][r]);
        else
          ((float*)Cv)[(size_t)row * N + col] = acc[mi][ni][r];
      }
    }
  }
}

// ---------------- RMSNorm(q,k) + RoPE + layout: Q,K->[B,H,S,HD], V->[B,H,HD,S]
// Q additionally pre-scaled by HD^-0.5 = 0.125 (folds softmax scale).
__global__ __launch_bounds__(256) void normrope(
    const unsigned short* __restrict__ qkv, const float* __restrict__ qw,
    const float* __restrict__ kw, unsigned short* __restrict__ Qb,
    unsigned short* __restrict__ Kb, unsigned short* __restrict__ Vt) {
  int tid = threadIdx.x;
  int d = tid & 63;
  int rl = tid >> 6;                      // wave id = local row
  int row_id = blockIdx.x * 4 + rl;       // [0, BS*H)
  int m = row_id >> 4;                    // token index, H=16
  int h = row_id & 15;
  int b = m >> 11;                        // S=2048
  int s = m & 2047;

  size_t base = (size_t)m * (3 * Dd) + h * 64 + d;
  float qv = bf2f(qkv[base]);
  float kv = bf2f(qkv[base + Dd]);
  float vv = bf2f(qkv[base + 2 * Dd]);

  float qss = qv * qv, kss = kv * kv;
#pragma unroll
  for (int o = 32; o > 0; o >>= 1) {
    qss += __shfl_xor(qss, o, 64);
    kss += __shfl_xor(kss, o, 64);
  }
  float qr = rsqrtf(qss * (1.0f / 64.0f) + 1e-6f) * 0.125f;  // fold HD^-0.5
  float kr = rsqrtf(kss * (1.0f / 64.0f) + 1e-6f);
  float qn = qv * qr * qw[d];
  float kn = kv * kr * kw[d];

  float ang = (float)s * __powf(10000.0f, -(float)(d & 31) * (1.0f / 32.0f));
  float cs, sn;
  sincosf(ang, &sn, &cs);
  float qp = __shfl_xor(qn, 32, 64);
  float kp = __shfl_xor(kn, 32, 64);
  float sg = (d < 32) ? -1.0f : 1.0f;
  float qo = qn * cs + sg * qp * sn;
  float ko = kn * cs + sg * kp * sn;

  size_t oqk = (((size_t)(b * Hh + h)) * Ss + s) * HDd + d;
  Qb[oqk] = f2bf(qo);
  Kb[oqk] = f2bf(ko);
  size_t ov = (((size_t)(b * Hh + h)) * HDd + d) * Ss + s;
  Vt[ov] = f2bf(vv);
}

// ---------------- flash attention with sink, causal, 64-row Q tile ----------
// LDS tiles are XOR-swizzled: slot (row, chunk16B) holds global chunk
// (chunk ^ (row&7)).  Readers hit all 32 banks (2-way = free) instead of the
// 16-way conflict of the naive 128B-stride layout (R1: 1.84e7 conflict cycles).
__global__ __launch_bounds__(256) void flash(
    const unsigned short* __restrict__ Qb, const unsigned short* __restrict__ Kb,
    const unsigned short* __restrict__ Vt, const float* __restrict__ sink,
    unsigned short* __restrict__ Ob) {
  __shared__ __align__(16) unsigned short Qs[64 * 64];
  __shared__ __align__(16) unsigned short Ks[64 * 64];
  __shared__ __align__(16) unsigned short Vs[64 * 64];    // V^T tile [d][kv]
  __shared__ __align__(16) unsigned short Ps[4][16 * 72]; // +8 pad per row

  int tid = threadIdx.x, lane = tid & 63, wave = tid >> 6;
  int quad = lane >> 4, l16 = lane & 15;
  int qt = (int)(gridDim.x - 1 - blockIdx.x);  // longest blocks first
  int h = blockIdx.y, b = blockIdx.z;
  int q0 = qt * 64;

  const unsigned short* Qg = Qb + ((size_t)(b * Hh + h) * Ss) * HDd;
  const unsigned short* Kg = Kb + ((size_t)(b * Hh + h) * Ss) * HDd;
  const unsigned short* Vg = Vt + ((size_t)(b * Hh + h) * HDd) * Ss;

  // staging coords: lane writes LDS bytes [tid*16) and [4096+tid*16)
  int off0 = tid * 16, off1 = 4096 + tid * 16;
  int sr0 = tid >> 3;            // tile row 0..31 (second round: +32, same &7)
  int sr1 = sr0 + 32;
  int sch = ((tid & 7) ^ (sr0 & 7)) * 8;  // swizzled source element offset

  gl_lds16(Qg + (size_t)(q0 + sr0) * 64 + sch, (char*)Qs + off0);
  gl_lds16(Qg + (size_t)(q0 + sr1) * 64 + sch, (char*)Qs + off1);

  float sk = sink[h];
  float m_i[4], l_i[4];
  f32x4 zero = {0.f, 0.f, 0.f, 0.f};
  f32x4 Oacc[4];
#pragma unroll
  for (int r = 0; r < 4; ++r) { m_i[r] = sk; l_i[r] = 1.0f; }
#pragma unroll
  for (int ni = 0; ni < 4; ++ni) Oacc[ni] = zero;

  int row_g = q0 + wave * 16 + quad * 4;  // + r
  int x0 = ((quad ^ (l16 & 7)) * 8);      // swizzled read offset, chunk=quad
  int x1 = x0 ^ 32;                       // chunk=quad+4 (bit2 flip)

  __syncthreads();  // Q staged (barrier drains vmcnt)
  bf16x8 aq0 = *(const bf16x8*)&Qs[(wave * 16 + l16) * 64 + x0];
  bf16x8 aq1 = *(const bf16x8*)&Qs[(wave * 16 + l16) * 64 + x1];

  for (int kt = 0; kt <= qt; ++kt) {
    int kv0 = kt * 64;
    gl_lds16(Kg + (size_t)(kv0 + sr0) * 64 + sch, (char*)Ks + off0);
    gl_lds16(Kg + (size_t)(kv0 + sr1) * 64 + sch, (char*)Ks + off1);
    gl_lds16(Vg + (size_t)sr0 * Ss + kv0 + sch, (char*)Vs + off0);
    gl_lds16(Vg + (size_t)sr1 * Ss + kv0 + sch, (char*)Vs + off1);
    __syncthreads();

    // S = Q K^T : per-wave 16(q) x 64(kv); Q pre-scaled by 0.125
    f32x4 sc[4];
#pragma unroll
    for (int ni = 0; ni < 4; ++ni) {
      bf16x8 bk0 = *(const bf16x8*)&Ks[(ni * 16 + l16) * 64 + x0];
      bf16x8 bk1 = *(const bf16x8*)&Ks[(ni * 16 + l16) * 64 + x1];
      sc[ni] = __builtin_amdgcn_mfma_f32_16x16x32_bf16(aq0, bk0, zero, 0, 0, 0);
      sc[ni] = __builtin_amdgcn_mfma_f32_16x16x32_bf16(aq1, bk1, sc[ni], 0, 0, 0);
    }

    bool diag = (kt == qt);
    float mt[4];
#pragma unroll
    for (int r = 0; r < 4; ++r) {
      float mm = -3.0e38f;
#pragma unroll
      for (int ni = 0; ni < 4; ++ni) {
        float v = sc[ni][r];
        if (diag && (kv0 + ni * 16 + l16 > row_g + r)) v = -1.0e38f;
        sc[ni][r] = v;
        mm = fmaxf(mm, v);
      }
      mt[r] = mm;
    }
#pragma unroll
    for (int o = 1; o < 16; o <<= 1)
#pragma unroll
      for (int r = 0; r < 4; ++r) mt[r] = fmaxf(mt[r], __shfl_xor(mt[r], o, 64));

    float alpha[4], rs[4];
#pragma unroll
    for (int r = 0; r < 4; ++r) {
      float mnew = fmaxf(m_i[r], mt[r]);
      alpha[r] = __expf(m_i[r] - mnew);
      m_i[r] = mnew;
      float ssum = 0.f;
#pragma unroll
      for (int ni = 0; ni < 4; ++ni) {
        float p = __expf(sc[ni][r] - mnew);
        sc[ni][r] = p;
        ssum += p;
      }
      rs[r] = ssum;
    }
#pragma unroll
    for (int o = 1; o < 16; o <<= 1)
#pragma unroll
      for (int r = 0; r < 4; ++r) rs[r] += __shfl_xor(rs[r], o, 64);
#pragma unroll
    for (int r = 0; r < 4; ++r) l_i[r] = l_i[r] * alpha[r] + rs[r];

    // P: C-layout -> LDS -> A-layout (per-wave region, no WG barrier needed)
#pragma unroll
    for (int ni = 0; ni < 4; ++ni)
#pragma unroll
      for (int r = 0; r < 4; ++r)
        Ps[wave][(quad * 4 + r) * 72 + ni * 16 + l16] = f2bf(sc[ni][r]);

#pragma unroll
    for (int ni = 0; ni < 4; ++ni)
#pragma unroll
      for (int r = 0; r < 4; ++r) Oacc[ni][r] *= alpha[r];

    asm volatile("s_waitcnt lgkmcnt(0)" ::: "memory");  // P writes visible in-wave
    bf16x8 ap0 = *(const bf16x8*)&Ps[wave][l16 * 72 + quad * 8];
    bf16x8 ap1 = *(const bf16x8*)&Ps[wave][l16 * 72 + 32 + quad * 8];
#pragma unroll
    for (int ni = 0; ni < 4; ++ni) {
      bf16x8 bv0 = *(const bf16x8*)&Vs[(ni * 16 + l16) * 64 + x0];
      bf16x8 bv1 = *(const bf16x8*)&Vs[(ni * 16 + l16) * 64 + x1];
      Oacc[ni] = __builtin_amdgcn_mfma_f32_16x16x32_bf16(ap0, bv0, Oacc[ni], 0, 0, 0);
      Oacc[ni] = __builtin_amdgcn_mfma_f32_16x16x32_bf16(ap1, bv1, Oacc[ni], 0, 0, 0);
    }
    __syncthreads();
  }

  // write attn out as [b, s, h*64+d] bf16 (A operand of final GEMM)
  float inv[4];
#pragma unroll
  for (int r = 0; r < 4; ++r) inv[r] = 1.0f / l_i[r];
#pragma unroll
  for (int ni = 0; ni < 4; ++ni)
#pragma unroll
    for (int r = 0; r < 4; ++r) {
      int srow = row_g + r;
      Ob[((size_t)b * Ss + srow) * Dd + h * 64 + ni * 16 + l16] =
          f2bf(Oacc[ni][r] * inv[r]);
    }
}

extern "C" void kernel_launch(void* const* d_in, const int* in_sizes, int n_in,
                              void* d_out, int out_size, void* d_ws, size_t ws_size,
                              hipStream_t stream) {
  const float* x  = (const float*)d_in[0];
  const float* wq = (const float*)d_in[1];
  const float* wk = (const float*)d_in[2];
  const float* wv = (const float*)d_in[3];
  const float* wo = (const float*)d_in[4];
  const float* qw = (const float*)d_in[5];
  const float* kw = (const float*)d_in[6];
  const float* sk = (const float*)d_in[7];

  char* ws = (char*)d_ws;
  const size_t MB = 1ull << 20;
  // layout (64 MB total): xb dies after GEMM1, attnb reuses its slot
  unsigned short* xb    = (unsigned short*)(ws + 0);       // 8 MB
  unsigned short* attnb = (unsigned short*)(ws + 0);       // 8 MB (after flash)
  unsigned short* wqkvb = (unsigned short*)(ws + 8 * MB);  // 6 MB
  unsigned short* wob   = (unsigned short*)(ws + 14 * MB); // 2 MB
  unsigned short* qkvb  = (unsigned short*)(ws + 16 * MB); // 24 MB
  unsigned short* Qb    = (unsigned short*)(ws + 40 * MB); // 8 MB
  unsigned short* Kb    = (unsigned short*)(ws + 48 * MB); // 8 MB
  unsigned short* Vt    = (unsigned short*)(ws + 56 * MB); // 8 MB

  cast_all<<<32768, 256, 0, stream>>>(x, wq, wk, wv, wo, xb, wqkvb, wob);
  gemm_bt<1><<<dim3(24, 32), 256, 0, stream>>>(xb, wqkvb, qkvb, BS, 3 * Dd, Dd);
  normrope<<<16384, 256, 0, stream>>>(qkvb, qw, kw, Qb, Kb, Vt);
  flash<<<dim3(32, Hh, Bb), 256, 0, stream>>>(Qb, Kb, Vt, sk, attnb);
  gemm_bt<0><<<dim3(8, 32), 256, 0, stream>>>(attnb, wob, d_out, BS, Dd, Dd);
}

// Round 3
// 234.630 us; speedup vs baseline: 1.4360x; 1.2571x over previous
//
#include <hip/hip_runtime.h>

#define Bb 2
#define Ss 2048
#define Dd 1024
#define Hh 16
#define HDd 64
#define BS (Bb * Ss)

typedef __attribute__((ext_vector_type(8))) __bf16 bf16x8;
typedef __attribute__((ext_vector_type(4))) float f32x4;

__device__ __forceinline__ unsigned short f2bf(float f) {
  union { float f; unsigned u; } v; v.f = f;
  unsigned r = v.u + 0x7fffu + ((v.u >> 16) & 1u);
  return (unsigned short)(r >> 16);
}
__device__ __forceinline__ unsigned short f2bf_fast(float f) {  // RN, no tie fix
  union { float f; unsigned u; } v; v.f = f;
  return (unsigned short)((v.u + 0x8000u) >> 16);
}
__device__ __forceinline__ float bf2f(unsigned short b) {
  union { unsigned u; float f; } v; v.u = ((unsigned)b) << 16;
  return v.f;
}

// async global->LDS, 16B per lane; LDS dest = wave-uniform base + lane*16
__device__ __forceinline__ void gl_lds16(const void* g, void* l) {
  __builtin_amdgcn_global_load_lds(
      (const __attribute__((address_space(1))) void*)g,
      (__attribute__((address_space(3))) void*)l, 16, 0, 0);
}

// ---------------- cast fp32 -> bf16 (x, stacked wq|wk|wv, wo) ----------------
__global__ __launch_bounds__(256) void cast_all(
    const float* __restrict__ x, const float* __restrict__ wq,
    const float* __restrict__ wk, const float* __restrict__ wv,
    const float* __restrict__ wo, unsigned short* __restrict__ xb,
    unsigned short* __restrict__ wqkvb, unsigned short* __restrict__ wob) {
  int i = blockIdx.x * 256 + threadIdx.x;
  const int NX = BS * Dd;      // 4M
  const int NW = Dd * Dd;      // 1M
  if (i < NX) { xb[i] = f2bf(x[i]); return; }
  int j = i - NX;
  if (j < NW) { wqkvb[j] = f2bf(wq[j]); return; }
  j -= NW;
  if (j < NW) { wqkvb[NW + j] = f2bf(wk[j]); return; }
  j -= NW;
  if (j < NW) { wqkvb[2 * NW + j] = f2bf(wv[j]); return; }
  j -= NW;
  if (j < NW) { wob[j] = f2bf(wo[j]); }
}

// ---------------- m97-style bf16 GEMM: C[m][n] = sum_k A[m][k] * Bw[n][k] ----
template <int OUT_BF16>
__global__ __launch_bounds__(256) void gemm_bt(
    const unsigned short* __restrict__ A, const unsigned short* __restrict__ Bw,
    void* __restrict__ Cv, int M, int N, int K) {
  __shared__ __align__(16) unsigned short As[128 * 32];
  __shared__ __align__(16) unsigned short Bs[128 * 32];
  const int tid = threadIdx.x;
  const int lane = tid & 63;
  const int quad = lane >> 4;
  const int l16 = lane & 15;
  const int wave = tid >> 6;
  const int wm = (wave >> 1) * 64;
  const int wn = (wave & 1) * 64;
  const int tile_m = blockIdx.y * 128;
  const int tile_n = blockIdx.x * 128;

  const int off0 = tid * 16;
  const int off1 = 4096 + tid * 16;
  const int r0 = off0 >> 6, e0 = (off0 & 63) >> 1;
  const int r1 = off1 >> 6, e1 = (off1 & 63) >> 1;

  const unsigned short* Ag0 = A + (size_t)(tile_m + r0) * K + e0;
  const unsigned short* Ag1 = A + (size_t)(tile_m + r1) * K + e1;
  const unsigned short* Bg0 = Bw + (size_t)(tile_n + r0) * K + e0;
  const unsigned short* Bg1 = Bw + (size_t)(tile_n + r1) * K + e1;

  f32x4 zero = {0.f, 0.f, 0.f, 0.f};
  f32x4 acc[4][4];
#pragma unroll
  for (int mi = 0; mi < 4; ++mi)
#pragma unroll
    for (int ni = 0; ni < 4; ++ni) acc[mi][ni] = zero;

  for (int k0 = 0; k0 < K; k0 += 32) {
    gl_lds16(Ag0 + k0, (char*)As + off0);
    gl_lds16(Ag1 + k0, (char*)As + off1);
    gl_lds16(Bg0 + k0, (char*)Bs + off0);
    gl_lds16(Bg1 + k0, (char*)Bs + off1);
    __syncthreads();
    bf16x8 af[4], bfv[4];
#pragma unroll
    for (int mi = 0; mi < 4; ++mi)
      af[mi] = *(const bf16x8*)&As[(wm + mi * 16 + l16) * 32 + quad * 8];
#pragma unroll
    for (int ni = 0; ni < 4; ++ni)
      bfv[ni] = *(const bf16x8*)&Bs[(wn + ni * 16 + l16) * 32 + quad * 8];
#pragma unroll
    for (int mi = 0; mi < 4; ++mi)
#pragma unroll
      for (int ni = 0; ni < 4; ++ni)
        acc[mi][ni] = __builtin_amdgcn_mfma_f32_16x16x32_bf16(
            af[mi], bfv[ni], acc[mi][ni], 0, 0, 0);
    __syncthreads();
  }

#pragma unroll
  for (int mi = 0; mi < 4; ++mi) {
#pragma unroll
    for (int ni = 0; ni < 4; ++ni) {
      int col = tile_n + wn + ni * 16 + l16;
#pragma unroll
      for (int r = 0; r < 4; ++r) {
        int row = tile_m + wm + mi * 16 + quad * 4 + r;
        if (OUT_BF16)
          ((unsigned short*)Cv)[(size_t)row * N + col] = f2bf(acc[mi][ni][r]);
        else
          ((float*)Cv)[(size_t)row * N + col] = acc[mi][ni][r];
      }
    }
  }
}

// ---------------- RMSNorm(q,k) + RoPE + layout: Q,K->[B,H,S,HD], V->[B,H,HD,S]
// Q additionally pre-scaled by HD^-0.5 = 0.125 (folds softmax scale).
__global__ __launch_bounds__(256) void normrope(
    const unsigned short* __restrict__ qkv, const float* __restrict__ qw,
    const float* __restrict__ kw, unsigned short* __restrict__ Qb,
    unsigned short* __restrict__ Kb, unsigned short* __restrict__ Vt) {
  int tid = threadIdx.x;
  int d = tid & 63;
  int rl = tid >> 6;
  int row_id = blockIdx.x * 4 + rl;
  int m = row_id >> 4;
  int h = row_id & 15;
  int b = m >> 11;
  int s = m & 2047;

  size_t base = (size_t)m * (3 * Dd) + h * 64 + d;
  float qv = bf2f(qkv[base]);
  float kv = bf2f(qkv[base + Dd]);
  float vv = bf2f(qkv[base + 2 * Dd]);

  float qss = qv * qv, kss = kv * kv;
#pragma unroll
  for (int o = 32; o > 0; o >>= 1) {
    qss += __shfl_xor(qss, o, 64);
    kss += __shfl_xor(kss, o, 64);
  }
  float qr = rsqrtf(qss * (1.0f / 64.0f) + 1e-6f) * 0.125f;
  float kr = rsqrtf(kss * (1.0f / 64.0f) + 1e-6f);
  float qn = qv * qr * qw[d];
  float kn = kv * kr * kw[d];

  float ang = (float)s * __powf(10000.0f, -(float)(d & 31) * (1.0f / 32.0f));
  float cs, sn;
  sincosf(ang, &sn, &cs);
  float qp = __shfl_xor(qn, 32, 64);
  float kp = __shfl_xor(kn, 32, 64);
  float sg = (d < 32) ? -1.0f : 1.0f;
  float qo = qn * cs + sg * qp * sn;
  float ko = kn * cs + sg * kp * sn;

  size_t oqk = (((size_t)(b * Hh + h)) * Ss + s) * HDd + d;
  Qb[oqk] = f2bf(qo);
  Kb[oqk] = f2bf(ko);
  size_t ov = (((size_t)(b * Hh + h)) * HDd + d) * Ss + s;
  Vt[ov] = f2bf(vv);
}

// ---------------- flash attention, S^T formulation, dbuf K/V, paired Q-tiles
// S^T = K·Q^T (operand-swapped MFMA): query = lane column (l16), kv = reg/quad.
// Softmax state m,l = per-lane scalars; reduce = 15 in-reg ops + 2 shuffles.
// O^T = V^T·P^T accumulated in C-layout; epilogue packs 4 d-values per store.
// K/V double-buffered: prefetch kt+1 issued post-barrier, overlaps compute.
// WG processes Q-tiles {31-bx, bx}: every WG does exactly 33 kv-tile iters.
__global__ __launch_bounds__(256) void flash(
    const unsigned short* __restrict__ Qb, const unsigned short* __restrict__ Kb,
    const unsigned short* __restrict__ Vt, const float* __restrict__ sink,
    unsigned short* __restrict__ Ob) {
  __shared__ __align__(16) unsigned short Qs[64 * 64];
  __shared__ __align__(16) unsigned short Ks[2][64 * 64];
  __shared__ __align__(16) unsigned short Vs[2][64 * 64];   // V^T tile [d][kv]
  __shared__ __align__(16) unsigned short Ps[4][16 * 72];   // [q][kv], +8 pad

  int tid = threadIdx.x, lane = tid & 63, wave = tid >> 6;
  int quad = lane >> 4, l16 = lane & 15;
  int bx = blockIdx.x;              // 0..15
  int h = blockIdx.y, b = blockIdx.z;

  const unsigned short* Qg = Qb + ((size_t)(b * Hh + h) * Ss) * HDd;
  const unsigned short* Kg = Kb + ((size_t)(b * Hh + h) * Ss) * HDd;
  const unsigned short* Vg = Vt + ((size_t)(b * Hh + h) * HDd) * Ss;

  int off0 = tid * 16, off1 = 4096 + tid * 16;
  int sr0 = tid >> 3, sr1 = sr0 + 32;
  int sch = ((tid & 7) ^ (sr0 & 7)) * 8;   // XOR-swizzled source chunk
  int x0 = ((quad ^ (l16 & 7)) * 8);       // swizzled read offset
  int x1 = x0 ^ 32;

  float sk = sink[h];
  f32x4 zero = {0.f, 0.f, 0.f, 0.f};

#pragma unroll 1
  for (int pass = 0; pass < 2; ++pass) {
    int qt = pass ? bx : 31 - bx;     // long tile first
    int q0 = qt * 64;
    int myq = q0 + wave * 16 + l16;   // this lane's query

    __syncthreads();  // prior pass done with all LDS buffers
    gl_lds16(Qg + (size_t)(q0 + sr0) * 64 + sch, (char*)Qs + off0);
    gl_lds16(Qg + (size_t)(q0 + sr1) * 64 + sch, (char*)Qs + off1);
    gl_lds16(Kg + (size_t)sr0 * 64 + sch, (char*)Ks[0] + off0);
    gl_lds16(Kg + (size_t)sr1 * 64 + sch, (char*)Ks[0] + off1);
    gl_lds16(Vg + (size_t)sr0 * Ss + sch, (char*)Vs[0] + off0);
    gl_lds16(Vg + (size_t)sr1 * Ss + sch, (char*)Vs[0] + off1);

    float m_i = sk, l_i = 1.0f;
    f32x4 Oacc[4];
#pragma unroll
    for (int ni = 0; ni < 4; ++ni) Oacc[ni] = zero;
    bf16x8 aq0, aq1;

    for (int kt = 0; kt <= qt; ++kt) {
      __syncthreads();  // buf[kt&1] (+ Q on kt==0) staged
      if (kt == 0) {
        aq0 = *(const bf16x8*)&Qs[(wave * 16 + l16) * 64 + x0];
        aq1 = *(const bf16x8*)&Qs[(wave * 16 + l16) * 64 + x1];
      }
      const unsigned short* Kt = Ks[kt & 1];
      const unsigned short* Vtile = Vs[kt & 1];
      int nxt = kt + 1;
      if (nxt <= qt) {  // prefetch next K/V while computing this tile
        gl_lds16(Kg + (size_t)(nxt * 64 + sr0) * 64 + sch, (char*)Ks[nxt & 1] + off0);
        gl_lds16(Kg + (size_t)(nxt * 64 + sr1) * 64 + sch, (char*)Ks[nxt & 1] + off1);
        gl_lds16(Vg + (size_t)sr0 * Ss + nxt * 64 + sch, (char*)Vs[nxt & 1] + off0);
        gl_lds16(Vg + (size_t)sr1 * Ss + nxt * 64 + sch, (char*)Vs[nxt & 1] + off1);
      }

      // S^T[kv][q] = K·Q^T : frag0 = K rows (m=kv), frag1 = Q rows (n=q)
      f32x4 sc[4];
#pragma unroll
      for (int ni = 0; ni < 4; ++ni) {
        bf16x8 bk0 = *(const bf16x8*)&Kt[(ni * 16 + l16) * 64 + x0];
        bf16x8 bk1 = *(const bf16x8*)&Kt[(ni * 16 + l16) * 64 + x1];
        sc[ni] = __builtin_amdgcn_mfma_f32_16x16x32_bf16(bk0, aq0, zero, 0, 0, 0);
        sc[ni] = __builtin_amdgcn_mfma_f32_16x16x32_bf16(bk1, aq1, sc[ni], 0, 0, 0);
      }

      bool diag = (kt == qt);
      float mt = -3.0e38f;
#pragma unroll
      for (int ni = 0; ni < 4; ++ni)
#pragma unroll
        for (int r = 0; r < 4; ++r) {
          float v = sc[ni][r];
          if (diag && (kt * 64 + ni * 16 + quad * 4 + r > myq)) v = -1.0e38f;
          sc[ni][r] = v;
          mt = fmaxf(mt, v);
        }
      mt = fmaxf(mt, __shfl_xor(mt, 16, 64));
      mt = fmaxf(mt, __shfl_xor(mt, 32, 64));

      float mnew = fmaxf(m_i, mt);
      float alpha = __expf(m_i - mnew);
      m_i = mnew;
      float ss = 0.f;
#pragma unroll
      for (int ni = 0; ni < 4; ++ni)
#pragma unroll
        for (int r = 0; r < 4; ++r) {
          float p = __expf(sc[ni][r] - mnew);
          sc[ni][r] = p;
          ss += p;
        }
      ss += __shfl_xor(ss, 16, 64);
      ss += __shfl_xor(ss, 32, 64);
      l_i = l_i * alpha + ss;

      // P[q][kv] packed write: 4 consecutive kv per (ni,quad)
#pragma unroll
      for (int ni = 0; ni < 4; ++ni) {
        ushort4 pk;
        pk.x = f2bf_fast(sc[ni][0]);
        pk.y = f2bf_fast(sc[ni][1]);
        pk.z = f2bf_fast(sc[ni][2]);
        pk.w = f2bf_fast(sc[ni][3]);
        *(ushort4*)&Ps[wave][l16 * 72 + ni * 16 + quad * 4] = pk;
      }

#pragma unroll
      for (int ni = 0; ni < 4; ++ni)
#pragma unroll
        for (int r = 0; r < 4; ++r) Oacc[ni][r] *= alpha;

      asm volatile("s_waitcnt lgkmcnt(0)" ::: "memory");
      bf16x8 ap0 = *(const bf16x8*)&Ps[wave][l16 * 72 + quad * 8];
      bf16x8 ap1 = *(const bf16x8*)&Ps[wave][l16 * 72 + 32 + quad * 8];

      // O^T[d][q] += V^T·P^T : frag0 = V^T rows (m=d), frag1 = P rows (n=q)
#pragma unroll
      for (int ni = 0; ni < 4; ++ni) {
        bf16x8 bv0 = *(const bf16x8*)&Vtile[(ni * 16 + l16) * 64 + x0];
        bf16x8 bv1 = *(const bf16x8*)&Vtile[(ni * 16 + l16) * 64 + x1];
        Oacc[ni] = __builtin_amdgcn_mfma_f32_16x16x32_bf16(bv0, ap0, Oacc[ni], 0, 0, 0);
        Oacc[ni] = __builtin_amdgcn_mfma_f32_16x16x32_bf16(bv1, ap1, Oacc[ni], 0, 0, 0);
      }
    }

    // epilogue: lane owns query myq, d = ni*16 + quad*4 + r
    float inv = 1.0f / l_i;
#pragma unroll
    for (int ni = 0; ni < 4; ++ni) {
      ushort4 ov;
      ov.x = f2bf(Oacc[ni][0] * inv);
      ov.y = f2bf(Oacc[ni][1] * inv);
      ov.z = f2bf(Oacc[ni][2] * inv);
      ov.w = f2bf(Oacc[ni][3] * inv);
      *(ushort4*)&Ob[((size_t)b * Ss + myq) * Dd + h * 64 + ni * 16 + quad * 4] = ov;
    }
  }
}

extern "C" void kernel_launch(void* const* d_in, const int* in_sizes, int n_in,
                              void* d_out, int out_size, void* d_ws, size_t ws_size,
                              hipStream_t stream) {
  const float* x  = (const float*)d_in[0];
  const float* wq = (const float*)d_in[1];
  const float* wk = (const float*)d_in[2];
  const float* wv = (const float*)d_in[3];
  const float* wo = (const float*)d_in[4];
  const float* qw = (const float*)d_in[5];
  const float* kw = (const float*)d_in[6];
  const float* sk = (const float*)d_in[7];

  char* ws = (char*)d_ws;
  const size_t MB = 1ull << 20;
  unsigned short* xb    = (unsigned short*)(ws + 0);       // 8 MB
  unsigned short* attnb = (unsigned short*)(ws + 0);       // 8 MB (after flash)
  unsigned short* wqkvb = (unsigned short*)(ws + 8 * MB);  // 6 MB
  unsigned short* wob   = (unsigned short*)(ws + 14 * MB); // 2 MB
  unsigned short* qkvb  = (unsigned short*)(ws + 16 * MB); // 24 MB
  unsigned short* Qb    = (unsigned short*)(ws + 40 * MB); // 8 MB
  unsigned short* Kb    = (unsigned short*)(ws + 48 * MB); // 8 MB
  unsigned short* Vt    = (unsigned short*)(ws + 56 * MB); // 8 MB

  cast_all<<<32768, 256, 0, stream>>>(x, wq, wk, wv, wo, xb, wqkvb, wob);
  gemm_bt<1><<<dim3(24, 32), 256, 0, stream>>>(xb, wqkvb, qkvb, BS, 3 * Dd, Dd);
  normrope<<<16384, 256, 0, stream>>>(qkvb, qw, kw, Qb, Kb, Vt);
  flash<<<dim3(16, Hh, Bb), 256, 0, stream>>>(Qb, Kb, Vt, sk, attnb);
  gemm_bt<0><<<dim3(8, 32), 256, 0, stream>>>(attnb, wob, d_out, BS, Dd, Dd);
}

// Round 4
// 232.245 us; speedup vs baseline: 1.4508x; 1.0103x over previous
//
#include <hip/hip_runtime.h>

#define Bb 2
#define Ss 2048
#define Dd 1024
#define Hh 16
#define HDd 64
#define BS (Bb * Ss)

typedef __attribute__((ext_vector_type(8))) __bf16 bf16x8;
typedef __attribute__((ext_vector_type(4))) float f32x4;

__device__ __forceinline__ unsigned short f2bf(float f) {
  union { float f; unsigned u; } v; v.f = f;
  unsigned r = v.u + 0x7fffu + ((v.u >> 16) & 1u);
  return (unsigned short)(r >> 16);
}
__device__ __forceinline__ unsigned short f2bf_fast(float f) {  // RN, no tie fix
  union { float f; unsigned u; } v; v.f = f;
  return (unsigned short)((v.u + 0x8000u) >> 16);
}
__device__ __forceinline__ float bf2f(unsigned short b) {
  union { unsigned u; float f; } v; v.u = ((unsigned)b) << 16;
  return v.f;
}

// async global->LDS, 16B per lane; LDS dest = wave-uniform base + lane*16
__device__ __forceinline__ void gl_lds16(const void* g, void* l) {
  __builtin_amdgcn_global_load_lds(
      (const __attribute__((address_space(1))) void*)g,
      (__attribute__((address_space(3))) void*)l, 16, 0, 0);
}

// ---------------- cast fp32 -> bf16, float4/ushort4 vectorized --------------
__global__ __launch_bounds__(256) void cast_all(
    const float4* __restrict__ x, const float4* __restrict__ wq,
    const float4* __restrict__ wk, const float4* __restrict__ wv,
    const float4* __restrict__ wo, ushort4* __restrict__ xb,
    ushort4* __restrict__ wqkvb, ushort4* __restrict__ wob) {
  int i = blockIdx.x * 256 + threadIdx.x;
  const int NX4 = BS * Dd / 4;   // 1M
  const int NW4 = Dd * Dd / 4;   // 256K
  const float4* src;
  ushort4* dst;
  int idx;
  if (i < NX4) { src = x; dst = xb; idx = i; }
  else if ((i -= NX4) < NW4) { src = wq; dst = wqkvb; idx = i; }
  else if ((i -= NW4) < NW4) { src = wk; dst = wqkvb + NW4; idx = i; }
  else if ((i -= NW4) < NW4) { src = wv; dst = wqkvb + 2 * NW4; idx = i; }
  else if ((i -= NW4) < NW4) { src = wo; dst = wob; idx = i; }
  else return;
  float4 v = src[idx];
  ushort4 o;
  o.x = f2bf(v.x); o.y = f2bf(v.y); o.z = f2bf(v.z); o.w = f2bf(v.w);
  dst[idx] = o;
}

// ---------------- bf16 GEMM 128x128: C[m][n] = sum_k A[m][k]*Bw[n][k] -------
// LDS XOR swizzle: slot chunk c of row r holds source chunk c ^ ((r>>1)&3).
// Read pattern then covers 8 distinct 16B slots / 16 lanes = 2-way = free
// (was 8-way = 2.94x, m136/m98).
template <int OUT_BF16>
__global__ __launch_bounds__(256) void gemm_bt(
    const unsigned short* __restrict__ A, const unsigned short* __restrict__ Bw,
    void* __restrict__ Cv, int M, int N, int K) {
  __shared__ __align__(16) unsigned short As[128 * 32];
  __shared__ __align__(16) unsigned short Bs[128 * 32];
  const int tid = threadIdx.x;
  const int lane = tid & 63;
  const int quad = lane >> 4;
  const int l16 = lane & 15;
  const int wave = tid >> 6;
  const int wm = (wave >> 1) * 64;
  const int wn = (wave & 1) * 64;
  const int tile_m = blockIdx.y * 128;
  const int tile_n = blockIdx.x * 128;

  const int off0 = tid * 16;
  const int off1 = 4096 + tid * 16;
  const int r0 = tid >> 2, r1 = r0 + 64;
  const int sch = (((tid & 3) ^ ((tid >> 3) & 3)) << 3);  // swizzled src elem
  const int xg = ((quad ^ ((l16 >> 1) & 3)) << 3);        // swizzled read elem

  const unsigned short* Ag0 = A + (size_t)(tile_m + r0) * K + sch;
  const unsigned short* Ag1 = A + (size_t)(tile_m + r1) * K + sch;
  const unsigned short* Bg0 = Bw + (size_t)(tile_n + r0) * K + sch;
  const unsigned short* Bg1 = Bw + (size_t)(tile_n + r1) * K + sch;

  f32x4 zero = {0.f, 0.f, 0.f, 0.f};
  f32x4 acc[4][4];
#pragma unroll
  for (int mi = 0; mi < 4; ++mi)
#pragma unroll
    for (int ni = 0; ni < 4; ++ni) acc[mi][ni] = zero;

  for (int k0 = 0; k0 < K; k0 += 32) {
    gl_lds16(Ag0 + k0, (char*)As + off0);
    gl_lds16(Ag1 + k0, (char*)As + off1);
    gl_lds16(Bg0 + k0, (char*)Bs + off0);
    gl_lds16(Bg1 + k0, (char*)Bs + off1);
    __syncthreads();
    bf16x8 af[4], bfv[4];
#pragma unroll
    for (int mi = 0; mi < 4; ++mi)
      af[mi] = *(const bf16x8*)&As[(wm + mi * 16 + l16) * 32 + xg];
#pragma unroll
    for (int ni = 0; ni < 4; ++ni)
      bfv[ni] = *(const bf16x8*)&Bs[(wn + ni * 16 + l16) * 32 + xg];
#pragma unroll
    for (int mi = 0; mi < 4; ++mi)
#pragma unroll
      for (int ni = 0; ni < 4; ++ni)
        acc[mi][ni] = __builtin_amdgcn_mfma_f32_16x16x32_bf16(
            af[mi], bfv[ni], acc[mi][ni], 0, 0, 0);
    __syncthreads();
  }

#pragma unroll
  for (int mi = 0; mi < 4; ++mi) {
#pragma unroll
    for (int ni = 0; ni < 4; ++ni) {
      int col = tile_n + wn + ni * 16 + l16;
#pragma unroll
      for (int r = 0; r < 4; ++r) {
        int row = tile_m + wm + mi * 16 + quad * 4 + r;
        if (OUT_BF16)
          ((unsigned short*)Cv)[(size_t)row * N + col] = f2bf(acc[mi][ni][r]);
        else
          ((float*)Cv)[(size_t)row * N + col] = acc[mi][ni][r];
      }
    }
  }
}

// ---------------- bf16 GEMM 128x64 tile (for N=1024 O-proj: 512 WGs, 2/CU) --
__global__ __launch_bounds__(256) void gemm_bt2(
    const unsigned short* __restrict__ A, const unsigned short* __restrict__ Bw,
    float* __restrict__ C, int M, int N, int K) {
  __shared__ __align__(16) unsigned short As[128 * 32];
  __shared__ __align__(16) unsigned short Bs[64 * 32];
  const int tid = threadIdx.x;
  const int lane = tid & 63;
  const int quad = lane >> 4;
  const int l16 = lane & 15;
  const int wave = tid >> 6;
  const int wm = (wave >> 1) * 64;
  const int wn = (wave & 1) * 32;
  const int tile_m = blockIdx.y * 128;
  const int tile_n = blockIdx.x * 64;

  const int off0 = tid * 16;
  const int off1 = 4096 + tid * 16;
  const int r0 = tid >> 2, r1 = r0 + 64;
  const int sch = (((tid & 3) ^ ((tid >> 3) & 3)) << 3);
  const int xg = ((quad ^ ((l16 >> 1) & 3)) << 3);

  const unsigned short* Ag0 = A + (size_t)(tile_m + r0) * K + sch;
  const unsigned short* Ag1 = A + (size_t)(tile_m + r1) * K + sch;
  const unsigned short* Bg0 = Bw + (size_t)(tile_n + r0) * K + sch;

  f32x4 zero = {0.f, 0.f, 0.f, 0.f};
  f32x4 acc[4][2];
#pragma unroll
  for (int mi = 0; mi < 4; ++mi)
#pragma unroll
    for (int ni = 0; ni < 2; ++ni) acc[mi][ni] = zero;

  for (int k0 = 0; k0 < K; k0 += 32) {
    gl_lds16(Ag0 + k0, (char*)As + off0);
    gl_lds16(Ag1 + k0, (char*)As + off1);
    gl_lds16(Bg0 + k0, (char*)Bs + off0);
    __syncthreads();
    bf16x8 af[4], bfv[2];
#pragma unroll
    for (int mi = 0; mi < 4; ++mi)
      af[mi] = *(const bf16x8*)&As[(wm + mi * 16 + l16) * 32 + xg];
#pragma unroll
    for (int ni = 0; ni < 2; ++ni)
      bfv[ni] = *(const bf16x8*)&Bs[(wn + ni * 16 + l16) * 32 + xg];
#pragma unroll
    for (int mi = 0; mi < 4; ++mi)
#pragma unroll
      for (int ni = 0; ni < 2; ++ni)
        acc[mi][ni] = __builtin_amdgcn_mfma_f32_16x16x32_bf16(
            af[mi], bfv[ni], acc[mi][ni], 0, 0, 0);
    __syncthreads();
  }

#pragma unroll
  for (int mi = 0; mi < 4; ++mi) {
#pragma unroll
    for (int ni = 0; ni < 2; ++ni) {
      int col = tile_n + wn + ni * 16 + l16;
#pragma unroll
      for (int r = 0; r < 4; ++r) {
        int row = tile_m + wm + mi * 16 + quad * 4 + r;
        C[(size_t)row * N + col] = acc[mi][ni][r];
      }
    }
  }
}

// ---------------- RMSNorm(q,k) + RoPE + layout: Q,K->[B,H,S,HD], V->[B,H,HD,S]
// Q additionally pre-scaled by HD^-0.5 = 0.125 (folds softmax scale).
__global__ __launch_bounds__(256) void normrope(
    const unsigned short* __restrict__ qkv, const float* __restrict__ qw,
    const float* __restrict__ kw, unsigned short* __restrict__ Qb,
    unsigned short* __restrict__ Kb, unsigned short* __restrict__ Vt) {
  int tid = threadIdx.x;
  int d = tid & 63;
  int rl = tid >> 6;
  int row_id = blockIdx.x * 4 + rl;
  int m = row_id >> 4;
  int h = row_id & 15;
  int b = m >> 11;
  int s = m & 2047;

  size_t base = (size_t)m * (3 * Dd) + h * 64 + d;
  float qv = bf2f(qkv[base]);
  float kv = bf2f(qkv[base + Dd]);
  float vv = bf2f(qkv[base + 2 * Dd]);

  float qss = qv * qv, kss = kv * kv;
#pragma unroll
  for (int o = 32; o > 0; o >>= 1) {
    qss += __shfl_xor(qss, o, 64);
    kss += __shfl_xor(kss, o, 64);
  }
  float qr = rsqrtf(qss * (1.0f / 64.0f) + 1e-6f) * 0.125f;
  float kr = rsqrtf(kss * (1.0f / 64.0f) + 1e-6f);
  float qn = qv * qr * qw[d];
  float kn = kv * kr * kw[d];

  float ang = (float)s * __powf(10000.0f, -(float)(d & 31) * (1.0f / 32.0f));
  float cs, sn;
  sincosf(ang, &sn, &cs);
  float qp = __shfl_xor(qn, 32, 64);
  float kp = __shfl_xor(kn, 32, 64);
  float sg = (d < 32) ? -1.0f : 1.0f;
  float qo = qn * cs + sg * qp * sn;
  float ko = kn * cs + sg * kp * sn;

  size_t oqk = (((size_t)(b * Hh + h)) * Ss + s) * HDd + d;
  Qb[oqk] = f2bf(qo);
  Kb[oqk] = f2bf(ko);
  size_t ov = (((size_t)(b * Hh + h)) * HDd + d) * Ss + s;
  Vt[ov] = f2bf(vv);
}

// ---------------- flash attention: S^T form, dbuf K/V, dynamic work queue ---
// - P overlays the Q tile (Q consumed into regs at kt==0; P uses the same
//   swizzled stride-64 layout) -> LDS 40 KB -> 3 WGs/CU (was 50 KB, 2/CU).
// - 768 WGs pull 1024 (qt,b,h) tiles off an atomic counter in descending-work
//   order: tail bounded by the 1-iter tiles, no static pairing needed.
__global__ __launch_bounds__(256) void flash(
    const unsigned short* __restrict__ Qb, const unsigned short* __restrict__ Kb,
    const unsigned short* __restrict__ Vt, const float* __restrict__ sink,
    unsigned short* __restrict__ Ob, int* __restrict__ counter) {
  __shared__ __align__(16) unsigned short QP[64 * 64];    // Q tile, then P
  __shared__ __align__(16) unsigned short Ks[2][64 * 64];
  __shared__ __align__(16) unsigned short Vs[2][64 * 64]; // V^T tile [d][kv]
  __shared__ int s_tile;

  int tid = threadIdx.x, lane = tid & 63, wave = tid >> 6;
  int quad = lane >> 4, l16 = lane & 15;

  int off0 = tid * 16, off1 = 4096 + tid * 16;
  int sr0 = tid >> 3, sr1 = sr0 + 32;
  int sch = ((tid & 7) ^ (sr0 & 7)) * 8;   // XOR-swizzled source chunk
  int x0 = ((quad ^ (l16 & 7)) * 8);       // swizzled read offset
  int x1 = x0 ^ 32;

  f32x4 zero = {0.f, 0.f, 0.f, 0.f};
  const int NTILES = 32 * Hh * Bb;  // 1024

  for (;;) {
    __syncthreads();  // all waves done with LDS of prior tile
    if (tid == 0) s_tile = atomicAdd(counter, 1);
    __syncthreads();
    int t = s_tile;
    if (t >= NTILES) return;
    int qt = 31 - (t >> 5);           // descending work
    int b = (t >> 4) & 1, h = t & 15;
    int q0 = qt * 64;
    int myq = q0 + wave * 16 + l16;   // this lane's query

    const unsigned short* Qg = Qb + ((size_t)(b * Hh + h) * Ss) * HDd;
    const unsigned short* Kg = Kb + ((size_t)(b * Hh + h) * Ss) * HDd;
    const unsigned short* Vg = Vt + ((size_t)(b * Hh + h) * HDd) * Ss;

    gl_lds16(Qg + (size_t)(q0 + sr0) * 64 + sch, (char*)QP + off0);
    gl_lds16(Qg + (size_t)(q0 + sr1) * 64 + sch, (char*)QP + off1);
    gl_lds16(Kg + (size_t)sr0 * 64 + sch, (char*)Ks[0] + off0);
    gl_lds16(Kg + (size_t)sr1 * 64 + sch, (char*)Ks[0] + off1);
    gl_lds16(Vg + (size_t)sr0 * Ss + sch, (char*)Vs[0] + off0);
    gl_lds16(Vg + (size_t)sr1 * Ss + sch, (char*)Vs[0] + off1);

    float m_i = sink[h], l_i = 1.0f;
    f32x4 Oacc[4];
#pragma unroll
    for (int ni = 0; ni < 4; ++ni) Oacc[ni] = zero;
    bf16x8 aq0, aq1;

    for (int kt = 0; kt <= qt; ++kt) {
      __syncthreads();  // buf[kt&1] (+ Q on kt==0) staged
      if (kt == 0) {
        aq0 = *(const bf16x8*)&QP[(wave * 16 + l16) * 64 + x0];
        aq1 = *(const bf16x8*)&QP[(wave * 16 + l16) * 64 + x1];
      }
      const unsigned short* Kt = Ks[kt & 1];
      const unsigned short* Vtile = Vs[kt & 1];
      int nxt = kt + 1;
      if (nxt <= qt) {  // prefetch next K/V while computing this tile
        gl_lds16(Kg + (size_t)(nxt * 64 + sr0) * 64 + sch, (char*)Ks[nxt & 1] + off0);
        gl_lds16(Kg + (size_t)(nxt * 64 + sr1) * 64 + sch, (char*)Ks[nxt & 1] + off1);
        gl_lds16(Vg + (size_t)sr0 * Ss + nxt * 64 + sch, (char*)Vs[nxt & 1] + off0);
        gl_lds16(Vg + (size_t)sr1 * Ss + nxt * 64 + sch, (char*)Vs[nxt & 1] + off1);
      }

      // S^T[kv][q] = K·Q^T : A-frag = K rows (m=kv), B-frag = Q rows (n=q)
      f32x4 sc[4];
#pragma unroll
      for (int ni = 0; ni < 4; ++ni) {
        bf16x8 bk0 = *(const bf16x8*)&Kt[(ni * 16 + l16) * 64 + x0];
        bf16x8 bk1 = *(const bf16x8*)&Kt[(ni * 16 + l16) * 64 + x1];
        sc[ni] = __builtin_amdgcn_mfma_f32_16x16x32_bf16(bk0, aq0, zero, 0, 0, 0);
        sc[ni] = __builtin_amdgcn_mfma_f32_16x16x32_bf16(bk1, aq1, sc[ni], 0, 0, 0);
      }

      bool diag = (kt == qt);
      float mt = -3.0e38f;
#pragma unroll
      for (int ni = 0; ni < 4; ++ni)
#pragma unroll
        for (int r = 0; r < 4; ++r) {
          float v = sc[ni][r];
          if (diag && (kt * 64 + ni * 16 + quad * 4 + r > myq)) v = -1.0e38f;
          sc[ni][r] = v;
          mt = fmaxf(mt, v);
        }
      mt = fmaxf(mt, __shfl_xor(mt, 16, 64));
      mt = fmaxf(mt, __shfl_xor(mt, 32, 64));

      float mnew = fmaxf(m_i, mt);
      float alpha = __expf(m_i - mnew);
      m_i = mnew;
      float ss = 0.f;
#pragma unroll
      for (int ni = 0; ni < 4; ++ni)
#pragma unroll
        for (int r = 0; r < 4; ++r) {
          float p = __expf(sc[ni][r] - mnew);
          sc[ni][r] = p;
          ss += p;
        }
      ss += __shfl_xor(ss, 16, 64);
      ss += __shfl_xor(ss, 32, 64);
      l_i = l_i * alpha + ss;

      // P[q][kv] into the Q region (wave-private rows), swizzled layout:
      // kv chunk c lands at slot c ^ (l16&7); write = b64, 2-way free.
#pragma unroll
      for (int ni = 0; ni < 4; ++ni) {
        ushort4 pk;
        pk.x = f2bf_fast(sc[ni][0]);
        pk.y = f2bf_fast(sc[ni][1]);
        pk.z = f2bf_fast(sc[ni][2]);
        pk.w = f2bf_fast(sc[ni][3]);
        int slot = ((ni * 2 + (quad >> 1)) ^ (l16 & 7)) * 8 + (quad & 1) * 4;
        *(ushort4*)&QP[(wave * 16 + l16) * 64 + slot] = pk;
      }

#pragma unroll
      for (int ni = 0; ni < 4; ++ni)
#pragma unroll
        for (int r = 0; r < 4; ++r) Oacc[ni][r] *= alpha;

      asm volatile("s_waitcnt lgkmcnt(0)" ::: "memory");  // P visible in-wave
      bf16x8 ap0 = *(const bf16x8*)&QP[(wave * 16 + l16) * 64 + x0];
      bf16x8 ap1 = *(const bf16x8*)&QP[(wave * 16 + l16) * 64 + x1];

      // O^T[d][q] += V^T·P^T : A-frag = V^T rows (m=d), B-frag = P rows (n=q)
#pragma unroll
      for (int ni = 0; ni < 4; ++ni) {
        bf16x8 bv0 = *(const bf16x8*)&Vtile[(ni * 16 + l16) * 64 + x0];
        bf16x8 bv1 = *(const bf16x8*)&Vtile[(ni * 16 + l16) * 64 + x1];
        Oacc[ni] = __builtin_amdgcn_mfma_f32_16x16x32_bf16(bv0, ap0, Oacc[ni], 0, 0, 0);
        Oacc[ni] = __builtin_amdgcn_mfma_f32_16x16x32_bf16(bv1, ap1, Oacc[ni], 0, 0, 0);
      }
    }

    // epilogue: lane owns query myq, d = ni*16 + quad*4 + r
    float inv = 1.0f / l_i;
#pragma unroll
    for (int ni = 0; ni < 4; ++ni) {
      ushort4 ov;
      ov.x = f2bf(Oacc[ni][0] * inv);
      ov.y = f2bf(Oacc[ni][1] * inv);
      ov.z = f2bf(Oacc[ni][2] * inv);
      ov.w = f2bf(Oacc[ni][3] * inv);
      *(ushort4*)&Ob[((size_t)b * Ss + myq) * Dd + h * 64 + ni * 16 + quad * 4] = ov;
    }
  }
}

extern "C" void kernel_launch(void* const* d_in, const int* in_sizes, int n_in,
                              void* d_out, int out_size, void* d_ws, size_t ws_size,
                              hipStream_t stream) {
  const float* x  = (const float*)d_in[0];
  const float* wq = (const float*)d_in[1];
  const float* wk = (const float*)d_in[2];
  const float* wv = (const float*)d_in[3];
  const float* wo = (const float*)d_in[4];
  const float* qw = (const float*)d_in[5];
  const float* kw = (const float*)d_in[6];
  const float* sk = (const float*)d_in[7];

  char* ws = (char*)d_ws;
  const size_t MB = 1ull << 20;
  unsigned short* xb    = (unsigned short*)(ws + 0);       // 8 MB
  unsigned short* attnb = (unsigned short*)(ws + 0);       // 8 MB (after flash)
  unsigned short* wqkvb = (unsigned short*)(ws + 8 * MB);  // 6 MB
  unsigned short* wob   = (unsigned short*)(ws + 14 * MB); // 2 MB
  unsigned short* qkvb  = (unsigned short*)(ws + 16 * MB); // 24 MB (dead after normrope)
  int*            cnt   = (int*)(ws + 16 * MB);            // overlays dead qkvb
  unsigned short* Qb    = (unsigned short*)(ws + 40 * MB); // 8 MB
  unsigned short* Kb    = (unsigned short*)(ws + 48 * MB); // 8 MB
  unsigned short* Vt    = (unsigned short*)(ws + 56 * MB); // 8 MB

  cast_all<<<9216, 256, 0, stream>>>(
      (const float4*)x, (const float4*)wq, (const float4*)wk, (const float4*)wv,
      (const float4*)wo, (ushort4*)xb, (ushort4*)wqkvb, (ushort4*)wob);
  gemm_bt<1><<<dim3(24, 32), 256, 0, stream>>>(xb, wqkvb, qkvb, BS, 3 * Dd, Dd);
  normrope<<<16384, 256, 0, stream>>>(qkvb, qw, kw, Qb, Kb, Vt);
  hipMemsetAsync(cnt, 0, 4, stream);
  flash<<<768, 256, 0, stream>>>(Qb, Kb, Vt, sk, attnb, cnt);
  gemm_bt2<<<dim3(16, 32), 256, 0, stream>>>(attnb, wob, (float*)d_out, BS, Dd, Dd);
}